// Round 18
// baseline (318.160 us; speedup 1.0000x reference)
//
#include <hip/hip_runtime.h>
#include <hip/hip_bf16.h>
#include <math.h>

typedef __attribute__((ext_vector_type(8))) short short8;
typedef __attribute__((ext_vector_type(16))) float f32x16;

#define NB 4096
#define DIM 128
#define NJ 16                  // j-splits: each block handles NB/NJ = 256 j's
// sqrt(20 * log2(e)) folded into BOTH operands: acc = 28.8539*dot (log2 units)
#define SQS 5.3715828f

// Raw v_exp_f32 (domain |x|<=28.9 is far from denormal; 1 instr, exact here).
#if __has_builtin(__builtin_amdgcn_exp2f)
#define EX2(x) __builtin_amdgcn_exp2f(x)
#else
#define EX2(x) exp2f(x)
#endif

__device__ inline unsigned short f2bf(float f) {
  unsigned int u = __builtin_bit_cast(unsigned int, f);
  u += 0x7FFFu + ((u >> 16) & 1u);
  return (unsigned short)(u >> 16);
}

__device__ inline float wave_sum(float v) {
#pragma unroll
  for (int off = 32; off >= 1; off >>= 1) v += __shfl_xor(v, off, 64);
  return v;
}

// Parallel int64-vs-int32 links detect (all odd words zero <=> int64) + out=0.
__global__ __launch_bounds__(64) void k_init(const int* links32, int* flag, float* out) {
  int t = threadIdx.x;
  bool ok = (links32[1 + 2 * t] == 0) && (links32[129 + 2 * t] == 0);
  unsigned long long m = __ballot(ok);
  if (t == 0) { *flag = (m == ~0ull) ? 1 : 0; out[0] = 0.0f; }
}

// Pair-per-wave gather + L2-normalize + f32 diag.
__global__ __launch_bounds__(256) void k_normalize(
    const float* __restrict__ emb, const int* __restrict__ links,
    const int* __restrict__ flag,
    unsigned short* __restrict__ Zic, unsigned short* __restrict__ Zjc,
    float* __restrict__ diagn) {
  int wid = threadIdx.x >> 6, lane = threadIdx.x & 63;
  int p = blockIdx.x * 4 + wid;   // pair index 0..4095
  int fl = *flag;
  int idx_i = fl ? links[4 * p + 0] : links[2 * p + 0];
  int idx_j = fl ? links[4 * p + 2] : links[2 * p + 1];
  const float* si = emb + (long long)idx_i * DIM;
  const float* sj = emb + (long long)idx_j * DIM;
  float a0 = si[lane], a1 = si[lane + 64];
  float b0 = sj[lane], b1 = sj[lane + 64];
  float sii = wave_sum(a0 * a0 + a1 * a1);
  float sjj = wave_sum(b0 * b0 + b1 * b1);
  float sij = wave_sum(a0 * b0 + a1 * b1);
  float ni = fmaxf(sqrtf(sii), 1e-12f);
  float nj = fmaxf(sqrtf(sjj), 1e-12f);
  if (lane == 0) diagn[p] = 20.0f * sij / (ni * nj);
  float wi = SQS / ni, wj = SQS / nj;
  size_t o0 = (((size_t)(lane >> 3) + 0) * NB + p) * 8 + (lane & 7);
  size_t o1 = (((size_t)(lane >> 3) + 8) * NB + p) * 8 + (lane & 7);
  Zic[o0] = f2bf(a0 * wi);
  Zic[o1] = f2bf(a1 * wi);
  Zjc[o0] = f2bf(b0 * wj);
  Zjc[o1] = f2bf(b1 * wj);
}

// ===== DIAGNOSTIC probe (results discarded into rdbg). =====
// R12-best structure, j-loop repeated 4x so dur > ~58us poison fills ->
// counters visible in rocprof top-5. MODE 0: full; MODE 1: epilogue removed
// (keep-alive consume); MODE 2: no LDS staging (direct global loads).
// R17 lesson: staging is TWO pieces per thread per side (q=0,1) — one-piece
// staging leaves k-chunks 8-15 stale (absmax 1.125).
template <int MODE>
__global__ __launch_bounds__(256, 2) void k_probe(
    const unsigned short* __restrict__ Zic, const unsigned short* __restrict__ Zjc,
    float* __restrict__ rdbg) {
  __shared__ unsigned short yt[2][2][4096];
  __shared__ float bufa[128], bufb[128];
  int tid = threadIdx.x, wid = tid >> 6, lane = tid & 63;
  if (tid < 128) { bufa[tid] = 0.0f; bufb[tid] = 0.0f; }
  if constexpr (MODE == 2) __syncthreads();  // init-safety (others sync at staging)

  int it0 = blockIdx.x * 128 + wid * 32;
  int jb = blockIdx.y * (NB / NJ);
  int lr = lane & 31;
  int hi = lane >> 5;

  short8 pj, pc;
  unsigned short blr = f2bf((float)lr);
#pragma unroll
  for (int e = 0; e < 8; ++e) { pj[e] = (short)blr; pc[e] = (short)0x3D80; }
  f32x16 pr = {}, pn = {};
  pr = __builtin_amdgcn_mfma_f32_32x32x16_bf16(pj, pc, pr, 0, 0, 0);
  pn = __builtin_amdgcn_mfma_f32_32x32x16_bf16(pc, pj, pn, 0, 0, 0);
  unsigned int dmask = 0;
  int imv[4] = {0, 0, 0, 0};
#pragma unroll
  for (int r = 0; r < 16; ++r) {
    int jm = (int)(pr[r] + 0.5f), im = (int)(pn[r] + 0.5f);
    dmask |= (unsigned)(jm == im) << r;
    imv[r >> 2] |= im << ((r & 3) * 8);
  }

  short8 xi[8], xj[8];
#pragma unroll
  for (int ks = 0; ks < 8; ++ks) {
    size_t o = ((size_t)(ks * 2 + hi) * NB + (it0 + lr)) * 8;
    xi[ks] = *reinterpret_cast<const short8*>(Zic + o);
    xj[ks] = *reinterpret_cast<const short8*>(Zjc + o);
  }

  float ra[16], rb[16];
#pragma unroll
  for (int r = 0; r < 16; ++r) { ra[r] = 0.0f; rb[r] = 0.0f; }

  for (int rep = 0; rep < 4; ++rep) {
    if constexpr (MODE != 2) {
#pragma unroll
      for (int q = 0; q < 2; ++q) {
        int p = q * 256 + tid;
        size_t go = ((size_t)(p >> 5) * NB + (jb + (p & 31))) * 8;
        *reinterpret_cast<short8*>(&yt[0][0][p * 8]) =
            *reinterpret_cast<const short8*>(Zjc + go);
        *reinterpret_cast<short8*>(&yt[0][1][p * 8]) =
            *reinterpret_cast<const short8*>(Zic + go);
      }
      __syncthreads();
    }
    for (int jt = 0; jt < 8; ++jt) {
      int cur = jt & 1, nxt = cur ^ 1;
      int j0 = jb + jt * 32;
      bool dt = (j0 == it0);
      short8 tj0, ti0, tj1, ti1;
      if (MODE != 2 && jt < 7) {
        int j0n = j0 + 32;
        size_t g0 = ((size_t)(tid >> 5) * NB + (j0n + (tid & 31))) * 8;
        size_t g1 = ((size_t)((tid + 256) >> 5) * NB + (j0n + (tid & 31))) * 8;
        tj0 = *reinterpret_cast<const short8*>(Zjc + g0);
        ti0 = *reinterpret_cast<const short8*>(Zic + g0);
        tj1 = *reinterpret_cast<const short8*>(Zjc + g1);
        ti1 = *reinterpret_cast<const short8*>(Zic + g1);
      }
      f32x16 pab = {}, pbb = {}, paa = {}, pba = {};
#pragma unroll
      for (int ks = 0; ks < 8; ++ks) {
        short8 yj, yi;
        if constexpr (MODE != 2) {
          int off = ((ks * 2 + hi) * 32 + lr) * 8;
          yj = *reinterpret_cast<const short8*>(&yt[cur][0][off]);
          yi = *reinterpret_cast<const short8*>(&yt[cur][1][off]);
        } else {
          size_t o = ((size_t)(ks * 2 + hi) * NB + (j0 + lr)) * 8;
          yj = *reinterpret_cast<const short8*>(Zjc + o);
          yi = *reinterpret_cast<const short8*>(Zic + o);
        }
        pab = __builtin_amdgcn_mfma_f32_32x32x16_bf16(yj, xi[ks], pab, 0, 0, 0);
        pbb = __builtin_amdgcn_mfma_f32_32x32x16_bf16(yj, xj[ks], pbb, 0, 0, 0);
        paa = __builtin_amdgcn_mfma_f32_32x32x16_bf16(yi, xi[ks], paa, 0, 0, 0);
        pba = __builtin_amdgcn_mfma_f32_32x32x16_bf16(yi, xj[ks], pba, 0, 0, 0);
      }
      if (MODE != 2 && jt < 7) {
        *reinterpret_cast<short8*>(&yt[nxt][0][tid * 8]) = tj0;
        *reinterpret_cast<short8*>(&yt[nxt][1][tid * 8]) = ti0;
        *reinterpret_cast<short8*>(&yt[nxt][0][(tid + 256) * 8]) = tj1;
        *reinterpret_cast<short8*>(&yt[nxt][1][(tid + 256) * 8]) = ti1;
      }
      if constexpr (MODE == 1) {
        ra[0] += pab[0] + paa[0];   // keep-alive, no exp/masks
        rb[0] += pbb[0] + pba[0];
      } else {
#pragma unroll
        for (int r = 0; r < 16; ++r) {
          float eab = EX2(pab[r]);
          float ebb = EX2(pbb[r]);
          float eaa = EX2(paa[r]);
          float eba = EX2(pba[r]);
          if (dt && ((dmask >> r) & 1u)) { ebb = 0.0f; eaa = 0.0f; }
          ra[r] += eab + eaa;
          rb[r] += ebb + eba;
        }
      }
      if constexpr (MODE != 2) __syncthreads();
    }
  }
#pragma unroll
  for (int r = 0; r < 16; ++r) {
    int im = (imv[r >> 2] >> ((r & 3) * 8)) & 0xFF;
    atomicAdd(&bufa[wid * 32 + im], ra[r]);
    atomicAdd(&bufb[wid * 32 + im], rb[r]);
  }
  __syncthreads();
  if (tid < 128) {
    rdbg[(size_t)blockIdx.y * NB + blockIdx.x * 128 + tid] = bufa[tid];
    rdbg[(size_t)(NJ + blockIdx.y) * NB + blockIdx.x * 128 + tid] = bufb[tid];
  }
}

// ===== REAL pass: verbatim Round-12 54.3us kernel (verified) =====
__global__ __launch_bounds__(256, 2) void k_pass(
    const unsigned short* __restrict__ Zic, const unsigned short* __restrict__ Zjc,
    float* __restrict__ rowp_a, float* __restrict__ rowp_b) {
  __shared__ unsigned short yt[2][2][4096];
  __shared__ float bufa[128], bufb[128];
  int tid = threadIdx.x, wid = tid >> 6, lane = tid & 63;
  if (tid < 128) { bufa[tid] = 0.0f; bufb[tid] = 0.0f; }

  int it0 = blockIdx.x * 128 + wid * 32;
  int jb = blockIdx.y * (NB / NJ);
  int lr = lane & 31;
  int hi = lane >> 5;

  short8 pj, pc;
  unsigned short blr = f2bf((float)lr);
#pragma unroll
  for (int e = 0; e < 8; ++e) { pj[e] = (short)blr; pc[e] = (short)0x3D80; }
  f32x16 pr = {}, pn = {};
  pr = __builtin_amdgcn_mfma_f32_32x32x16_bf16(pj, pc, pr, 0, 0, 0);
  pn = __builtin_amdgcn_mfma_f32_32x32x16_bf16(pc, pj, pn, 0, 0, 0);
  unsigned int dmask = 0;
  int imv[4] = {0, 0, 0, 0};
#pragma unroll
  for (int r = 0; r < 16; ++r) {
    int jm = (int)(pr[r] + 0.5f), im = (int)(pn[r] + 0.5f);
    dmask |= (unsigned)(jm == im) << r;
    imv[r >> 2] |= im << ((r & 3) * 8);
  }

  short8 xi[8], xj[8];
#pragma unroll
  for (int ks = 0; ks < 8; ++ks) {
    size_t o = ((size_t)(ks * 2 + hi) * NB + (it0 + lr)) * 8;
    xi[ks] = *reinterpret_cast<const short8*>(Zic + o);
    xj[ks] = *reinterpret_cast<const short8*>(Zjc + o);
  }

  float ra[16], rb[16];
#pragma unroll
  for (int r = 0; r < 16; ++r) { ra[r] = 0.0f; rb[r] = 0.0f; }

  // prologue: stage tile 0 (TWO pieces per thread per side — all 16 chunks)
#pragma unroll
  for (int q = 0; q < 2; ++q) {
    int p = q * 256 + tid;
    size_t go = ((size_t)(p >> 5) * NB + (jb + (p & 31))) * 8;
    *reinterpret_cast<short8*>(&yt[0][0][p * 8]) =
        *reinterpret_cast<const short8*>(Zjc + go);
    *reinterpret_cast<short8*>(&yt[0][1][p * 8]) =
        *reinterpret_cast<const short8*>(Zic + go);
  }
  __syncthreads();

  for (int jt = 0; jt < 8; ++jt) {
    int cur = jt & 1, nxt = cur ^ 1;
    int j0 = jb + jt * 32;
    bool dt = (j0 == it0);
    short8 tj0, ti0, tj1, ti1;
    if (jt < 7) {
      int j0n = j0 + 32;
      size_t g0 = ((size_t)(tid >> 5) * NB + (j0n + (tid & 31))) * 8;
      size_t g1 = ((size_t)((tid + 256) >> 5) * NB + (j0n + (tid & 31))) * 8;
      tj0 = *reinterpret_cast<const short8*>(Zjc + g0);
      ti0 = *reinterpret_cast<const short8*>(Zic + g0);
      tj1 = *reinterpret_cast<const short8*>(Zjc + g1);
      ti1 = *reinterpret_cast<const short8*>(Zic + g1);
    }
    f32x16 pab = {}, pbb = {}, paa = {}, pba = {};
#pragma unroll
    for (int ks = 0; ks < 8; ++ks) {
      int off = ((ks * 2 + hi) * 32 + lr) * 8;
      short8 yj = *reinterpret_cast<const short8*>(&yt[cur][0][off]);
      short8 yi = *reinterpret_cast<const short8*>(&yt[cur][1][off]);
      pab = __builtin_amdgcn_mfma_f32_32x32x16_bf16(yj, xi[ks], pab, 0, 0, 0);
      pbb = __builtin_amdgcn_mfma_f32_32x32x16_bf16(yj, xj[ks], pbb, 0, 0, 0);
      paa = __builtin_amdgcn_mfma_f32_32x32x16_bf16(yi, xi[ks], paa, 0, 0, 0);
      pba = __builtin_amdgcn_mfma_f32_32x32x16_bf16(yi, xj[ks], pba, 0, 0, 0);
    }
    if (jt < 7) {
      *reinterpret_cast<short8*>(&yt[nxt][0][tid * 8]) = tj0;
      *reinterpret_cast<short8*>(&yt[nxt][1][tid * 8]) = ti0;
      *reinterpret_cast<short8*>(&yt[nxt][0][(tid + 256) * 8]) = tj1;
      *reinterpret_cast<short8*>(&yt[nxt][1][(tid + 256) * 8]) = ti1;
    }
#pragma unroll
    for (int r = 0; r < 16; ++r) {
      float eab = EX2(pab[r]);
      float ebb = EX2(pbb[r]);
      float eaa = EX2(paa[r]);
      float eba = EX2(pba[r]);
      if (dt && ((dmask >> r) & 1u)) { ebb = 0.0f; eaa = 0.0f; }
      ra[r] += eab + eaa;
      rb[r] += ebb + eba;
    }
    __syncthreads();
  }
#pragma unroll
  for (int r = 0; r < 16; ++r) {
    int im = (imv[r >> 2] >> ((r & 3) * 8)) & 0xFF;
    atomicAdd(&bufa[wid * 32 + im], ra[r]);
    atomicAdd(&bufb[wid * 32 + im], rb[r]);
  }
  __syncthreads();
  if (tid < 128) {
    rowp_a[(size_t)blockIdx.y * NB + blockIdx.x * 128 + tid] = bufa[tid];
    rowp_b[(size_t)blockIdx.y * NB + blockIdx.x * 128 + tid] = bufb[tid];
  }
}

// loss = mean(0.5*(ln sa + ln sb) - diagn)
__global__ __launch_bounds__(256) void k_final(
    const float* __restrict__ rowp_a, const float* __restrict__ rowp_b,
    const float* __restrict__ diagn, float* __restrict__ out) {
  int i = blockIdx.x * 256 + threadIdx.x;
  float sa = 0.0f, sb = 0.0f;
#pragma unroll
  for (int y = 0; y < 16; ++y) {
    sa += rowp_a[(size_t)y * NB + i];
    sb += rowp_b[(size_t)y * NB + i];
  }
  float v = 0.5f * (logf(sa) + logf(sb)) - diagn[i];
  v = wave_sum(v);
  __shared__ float sred[4];
  if ((threadIdx.x & 63) == 0) sred[threadIdx.x >> 6] = v;
  __syncthreads();
  if (threadIdx.x == 0)
    atomicAdd(out, (sred[0] + sred[1] + sred[2] + sred[3]) * (1.0f / NB));
}

extern "C" void kernel_launch(void* const* d_in, const int* in_sizes, int n_in,
                              void* d_out, int out_size, void* d_ws, size_t ws_size,
                              hipStream_t stream) {
  const float* emb = (const float*)d_in[0];
  const int* links = (const int*)d_in[1];
  char* ws = (char*)d_ws;
  unsigned short* Zic = (unsigned short*)(ws + 0);       // 1 MB
  unsigned short* Zjc = (unsigned short*)(ws + 1048576); // 1 MB
  float* rowp_a = (float*)(ws + 2097152);                // 256 KB
  float* rowp_b = (float*)(ws + 2359296);                // 256 KB
  float* diagn = (float*)(ws + 2621440);                 // 16 KB
  int* flag = (int*)(ws + 2637824);                      // 4 B
  float* rdbg = (float*)(ws + 3145728);                  // 512 KB, diagnostics only
  float* out = (float*)d_out;

  hipLaunchKernelGGL(k_init, dim3(1), dim3(64), 0, stream, links, flag, out);
  hipLaunchKernelGGL(k_normalize, dim3(1024), dim3(256), 0, stream,
                     emb, links, flag, Zic, Zjc, diagn);
  // --- diagnostics (discarded output, 4x repeat for counter visibility) ---
  hipLaunchKernelGGL((k_probe<0>), dim3(32, NJ), dim3(256), 0, stream, Zic, Zjc, rdbg);
  hipLaunchKernelGGL((k_probe<1>), dim3(32, NJ), dim3(256), 0, stream, Zic, Zjc, rdbg);
  hipLaunchKernelGGL((k_probe<2>), dim3(32, NJ), dim3(256), 0, stream, Zic, Zjc, rdbg);
  // --- real pass ---
  hipLaunchKernelGGL(k_pass, dim3(32, NJ), dim3(256), 0, stream,
                     Zic, Zjc, rowp_a, rowp_b);
  hipLaunchKernelGGL(k_final, dim3(16), dim3(256), 0, stream,
                     rowp_a, rowp_b, diagn, out);
}

// Round 19
// 54.940 us; speedup vs baseline: 5.7911x; 5.7911x over previous
//
#include <hip/hip_runtime.h>
#include <hip/hip_bf16.h>
#include <math.h>

typedef __attribute__((ext_vector_type(8))) short short8;
typedef __attribute__((ext_vector_type(16))) float f32x16;

#define NB 4096
#define DIM 128
#define NJ 16                  // j-splits: each block handles NB/NJ = 256 j's
// sqrt(20 * log2(e)) folded into BOTH operands: acc = 28.8539*dot (log2 units)
#define SQS 5.3715828f

// Raw v_exp_f32 (domain |x|<=28.9 is far from denormal; 1 instr, exact here).
#if __has_builtin(__builtin_amdgcn_exp2f)
#define EX2(x) __builtin_amdgcn_exp2f(x)
#else
#define EX2(x) exp2f(x)
#endif

__device__ inline unsigned short f2bf(float f) {
  unsigned int u = __builtin_bit_cast(unsigned int, f);
  u += 0x7FFFu + ((u >> 16) & 1u);
  return (unsigned short)(u >> 16);
}

__device__ inline float wave_sum(float v) {
#pragma unroll
  for (int off = 32; off >= 1; off >>= 1) v += __shfl_xor(v, off, 64);
  return v;
}

// Parallel int64-vs-int32 links detect (all odd words zero <=> int64) + out=0.
__global__ __launch_bounds__(64) void k_init(const int* links32, int* flag, float* out) {
  int t = threadIdx.x;
  bool ok = (links32[1 + 2 * t] == 0) && (links32[129 + 2 * t] == 0);
  unsigned long long m = __ballot(ok);
  if (t == 0) { *flag = (m == ~0ull) ? 1 : 0; out[0] = 0.0f; }
}

// Pair-per-wave gather + L2-normalize + f32 diag.
__global__ __launch_bounds__(256) void k_normalize(
    const float* __restrict__ emb, const int* __restrict__ links,
    const int* __restrict__ flag,
    unsigned short* __restrict__ Zic, unsigned short* __restrict__ Zjc,
    float* __restrict__ diagn) {
  int wid = threadIdx.x >> 6, lane = threadIdx.x & 63;
  int p = blockIdx.x * 4 + wid;   // pair index 0..4095
  int fl = *flag;
  int idx_i = fl ? links[4 * p + 0] : links[2 * p + 0];
  int idx_j = fl ? links[4 * p + 2] : links[2 * p + 1];
  const float* si = emb + (long long)idx_i * DIM;
  const float* sj = emb + (long long)idx_j * DIM;
  float a0 = si[lane], a1 = si[lane + 64];
  float b0 = sj[lane], b1 = sj[lane + 64];
  float sii = wave_sum(a0 * a0 + a1 * a1);
  float sjj = wave_sum(b0 * b0 + b1 * b1);
  float sij = wave_sum(a0 * b0 + a1 * b1);
  float ni = fmaxf(sqrtf(sii), 1e-12f);
  float nj = fmaxf(sqrtf(sjj), 1e-12f);
  if (lane == 0) diagn[p] = 20.0f * sij / (ni * nj);
  float wi = SQS / ni, wj = SQS / nj;
  size_t o0 = (((size_t)(lane >> 3) + 0) * NB + p) * 8 + (lane & 7);
  size_t o1 = (((size_t)(lane >> 3) + 8) * NB + p) * 8 + (lane & 7);
  Zic[o0] = f2bf(a0 * wi);
  Zic[o1] = f2bf(a1 * wi);
  Zjc[o0] = f2bf(b0 * wj);
  Zjc[o1] = f2bf(b1 * wj);
}

// Side-split pass (R18 ablation: epilogue = 95% of cost, dependency-stall-
// bound at 2 waves/SIMD with ~200 total regs). Each wave owns ONE side's
// x rows and runs its two chains SEQUENTIALLY (one 16-AGPR acc live at a
// time): ~110 total regs -> 4 waves/SIMD under __launch_bounds__(256,4)'s
// 128-reg budget. z=0 (side A): AB=yj.xi (no skip) + AA=yi.xi (skip) -> ra.
// z=1 (side B): BB=yj.xj (skip) + BA=yi.xj (no skip) -> rb.
// Staging/barrier pattern verbatim R12 (verified); diag branch hoisted
// wave-uniform so non-diag tiles run exp+add only.
__global__ __launch_bounds__(256, 4) void k_pass(
    const unsigned short* __restrict__ Zic, const unsigned short* __restrict__ Zjc,
    float* __restrict__ rowp) {
  __shared__ unsigned short yt[2][2][4096];  // [dbuf][0=yj,1=yi] 32 KB
  __shared__ float bufr[128];
  int tid = threadIdx.x, wid = tid >> 6, lane = tid & 63;
  int side = blockIdx.z;
  if (tid < 128) bufr[tid] = 0.0f;

  int it0 = blockIdx.x * 128 + wid * 32;
  int jb = blockIdx.y * (NB / NJ);
  int lr = lane & 31;
  int hi = lane >> 5;

  // --- dual per-reg layout probe (verified R3-R18) ---
  short8 pj, pc;
  unsigned short blr = f2bf((float)lr);
#pragma unroll
  for (int e = 0; e < 8; ++e) { pj[e] = (short)blr; pc[e] = (short)0x3D80; }
  f32x16 pr = {}, pn = {};
  pr = __builtin_amdgcn_mfma_f32_32x32x16_bf16(pj, pc, pr, 0, 0, 0);
  pn = __builtin_amdgcn_mfma_f32_32x32x16_bf16(pc, pj, pn, 0, 0, 0);
  unsigned int dmask = 0;
  int imv[4] = {0, 0, 0, 0};
#pragma unroll
  for (int r = 0; r < 16; ++r) {
    int jm = (int)(pr[r] + 0.5f), im = (int)(pn[r] + 0.5f);
    dmask |= (unsigned)(jm == im) << r;
    imv[r >> 2] |= im << ((r & 3) * 8);
  }

  // X fragments: 32 rows of this wave's side only (32 VGPR)
  const unsigned short* Xs = side ? Zjc : Zic;
  short8 x[8];
#pragma unroll
  for (int ks = 0; ks < 8; ++ks)
    x[ks] = *reinterpret_cast<const short8*>(
        Xs + ((size_t)(ks * 2 + hi) * NB + (it0 + lr)) * 8);

  float rs[16];
#pragma unroll
  for (int r = 0; r < 16; ++r) rs[r] = 0.0f;

  // prologue: stage tile 0 (TWO pieces per thread per side — all 16 chunks)
#pragma unroll
  for (int q = 0; q < 2; ++q) {
    int p = q * 256 + tid;
    size_t go = ((size_t)(p >> 5) * NB + (jb + (p & 31))) * 8;
    *reinterpret_cast<short8*>(&yt[0][0][p * 8]) =
        *reinterpret_cast<const short8*>(Zjc + go);
    *reinterpret_cast<short8*>(&yt[0][1][p * 8]) =
        *reinterpret_cast<const short8*>(Zic + go);
  }
  __syncthreads();

  for (int jt = 0; jt < 8; ++jt) {
    int cur = jt & 1, nxt = cur ^ 1;
    int j0 = jb + jt * 32;
    bool dt = (j0 == it0);
    short8 tj0, ti0, tj1, ti1;
    if (jt < 7) {  // issue-early: next tile's 4 global loads
      int j0n = j0 + 32;
      size_t g0 = ((size_t)(tid >> 5) * NB + (j0n + (tid & 31))) * 8;
      size_t g1 = ((size_t)((tid + 256) >> 5) * NB + (j0n + (tid & 31))) * 8;
      tj0 = *reinterpret_cast<const short8*>(Zjc + g0);
      ti0 = *reinterpret_cast<const short8*>(Zic + g0);
      tj1 = *reinterpret_cast<const short8*>(Zjc + g1);
      ti1 = *reinterpret_cast<const short8*>(Zic + g1);
    }
    // ---- chain 0: yj-based (AB for side A, BB for side B) ----
    {
      f32x16 a = {};
#pragma unroll
      for (int ks = 0; ks < 8; ++ks) {
        int off = ((ks * 2 + hi) * 32 + lr) * 8;
        short8 y = *reinterpret_cast<const short8*>(&yt[cur][0][off]);
        a = __builtin_amdgcn_mfma_f32_32x32x16_bf16(y, x[ks], a, 0, 0, 0);
      }
      if (side && dt) {  // BB diag skip (wave-uniform branch)
#pragma unroll
        for (int r = 0; r < 16; ++r) {
          float e = EX2(a[r]);
          if ((dmask >> r) & 1u) e = 0.0f;
          rs[r] += e;
        }
      } else {
#pragma unroll
        for (int r = 0; r < 16; ++r) rs[r] += EX2(a[r]);
      }
    }
    // ---- chain 1: yi-based (AA for side A, BA for side B) ----
    {
      f32x16 a = {};
#pragma unroll
      for (int ks = 0; ks < 8; ++ks) {
        int off = ((ks * 2 + hi) * 32 + lr) * 8;
        short8 y = *reinterpret_cast<const short8*>(&yt[cur][1][off]);
        a = __builtin_amdgcn_mfma_f32_32x32x16_bf16(y, x[ks], a, 0, 0, 0);
      }
      if (jt < 7) {  // write-late: staging lands under the epilogue below
        *reinterpret_cast<short8*>(&yt[nxt][0][tid * 8]) = tj0;
        *reinterpret_cast<short8*>(&yt[nxt][1][tid * 8]) = ti0;
        *reinterpret_cast<short8*>(&yt[nxt][0][(tid + 256) * 8]) = tj1;
        *reinterpret_cast<short8*>(&yt[nxt][1][(tid + 256) * 8]) = ti1;
      }
      if (!side && dt) {  // AA diag skip
#pragma unroll
        for (int r = 0; r < 16; ++r) {
          float e = EX2(a[r]);
          if ((dmask >> r) & 1u) e = 0.0f;
          rs[r] += e;
        }
      } else {
#pragma unroll
        for (int r = 0; r < 16; ++r) rs[r] += EX2(a[r]);
      }
    }
    __syncthreads();
  }
  // LDS reduce (2 lanes x 16 regs share each output row)
#pragma unroll
  for (int r = 0; r < 16; ++r) {
    int im = (imv[r >> 2] >> ((r & 3) * 8)) & 0xFF;
    atomicAdd(&bufr[wid * 32 + im], rs[r]);
  }
  __syncthreads();
  if (tid < 128)
    rowp[((size_t)side * NJ + blockIdx.y) * NB + blockIdx.x * 128 + tid] = bufr[tid];
}

// loss = mean(0.5*(ln sa + ln sb) - diagn)   (e^{+20} scale cancels in ln)
__global__ __launch_bounds__(256) void k_final(
    const float* __restrict__ rowp, const float* __restrict__ diagn,
    float* __restrict__ out) {
  int i = blockIdx.x * 256 + threadIdx.x;
  float sa = 0.0f, sb = 0.0f;
#pragma unroll
  for (int y = 0; y < NJ; ++y) {
    sa += rowp[(size_t)(0 * NJ + y) * NB + i];
    sb += rowp[(size_t)(1 * NJ + y) * NB + i];
  }
  float v = 0.5f * (logf(sa) + logf(sb)) - diagn[i];
  v = wave_sum(v);
  __shared__ float sred[4];
  if ((threadIdx.x & 63) == 0) sred[threadIdx.x >> 6] = v;
  __syncthreads();
  if (threadIdx.x == 0)
    atomicAdd(out, (sred[0] + sred[1] + sred[2] + sred[3]) * (1.0f / NB));
}

extern "C" void kernel_launch(void* const* d_in, const int* in_sizes, int n_in,
                              void* d_out, int out_size, void* d_ws, size_t ws_size,
                              hipStream_t stream) {
  const float* emb = (const float*)d_in[0];
  const int* links = (const int*)d_in[1];
  char* ws = (char*)d_ws;
  unsigned short* Zic = (unsigned short*)(ws + 0);       // 1 MB
  unsigned short* Zjc = (unsigned short*)(ws + 1048576); // 1 MB
  float* rowp = (float*)(ws + 2097152);                  // 2*16*4096*4 = 512 KB
  float* diagn = (float*)(ws + 2621440);                 // 16 KB
  int* flag = (int*)(ws + 2637824);                      // 4 B
  float* out = (float*)d_out;

  hipLaunchKernelGGL(k_init, dim3(1), dim3(64), 0, stream, links, flag, out);
  hipLaunchKernelGGL(k_normalize, dim3(1024), dim3(256), 0, stream,
                     emb, links, flag, Zic, Zjc, diagn);
  hipLaunchKernelGGL(k_pass, dim3(32, NJ, 2), dim3(256), 0, stream,
                     Zic, Zjc, rowp);
  hipLaunchKernelGGL(k_final, dim3(16), dim3(256), 0, stream,
                     rowp, diagn, out);
}